// Round 20
// baseline (161.692 us; speedup 1.0000x reference)
//
#include <hip/hip_runtime.h>
#include <hip/hip_bf16.h>
#include <stdint.h>

#define D_MODEL 1024
#define NHEAD 16
#define SEQ 2048
#define BATCH 4
#define DK 64
#define QKVSTR 3072

typedef __attribute__((ext_vector_type(8))) short short8;
typedef __attribute__((ext_vector_type(4))) float f32x4;
typedef __attribute__((ext_vector_type(16))) float f32x16;

#if __has_builtin(__builtin_amdgcn_exp2f)
#define EXP2(x) __builtin_amdgcn_exp2f(x)
#else
#define EXP2(x) exp2f(x)
#endif

__device__ inline unsigned short f2bf(float f) {
  unsigned int u = __builtin_bit_cast(unsigned int, f);
  unsigned int r = (u + 0x7fffu + ((u >> 16) & 1u)) >> 16;
  return (unsigned short)r;
}

__device__ inline unsigned int cvt_pk_bf16(float lo, float hi) {
  unsigned int d;
  asm("v_cvt_pk_bf16_f32 %0, %1, %2" : "=v"(d) : "v"(lo), "v"(hi));
  return d;
}

#define GLOAD_LDS16(g, l) \
  __builtin_amdgcn_global_load_lds((const __attribute__((address_space(1))) unsigned int*)(g), \
      (__attribute__((address_space(3))) unsigned int*)(l), 16, 0, 0)

// ---------------- f32 -> bf16 convert ----------------
__global__ void cvt_kernel(const float* __restrict__ in, unsigned short* __restrict__ out, int n) {
  int i = (blockIdx.x * 256 + threadIdx.x) * 8;
  if (i >= n) return;
  const float4* p = (const float4*)(in + i);
  float4 a = p[0], b = p[1];
  union { unsigned short u[8]; uint4 v; } r;
  r.u[0] = f2bf(a.x); r.u[1] = f2bf(a.y); r.u[2] = f2bf(a.z); r.u[3] = f2bf(a.w);
  r.u[4] = f2bf(b.x); r.u[5] = f2bf(b.y); r.u[6] = f2bf(b.z); r.u[7] = f2bf(b.w);
  *(uint4*)(out + i) = r.v;
}

// 4 weight matrices in one dispatch; outputs contiguous at out + by*n
__global__ void cvt4_kernel(const float* __restrict__ i0, const float* __restrict__ i1,
                            const float* __restrict__ i2, const float* __restrict__ i3,
                            unsigned short* __restrict__ out, int n) {
  const int by = blockIdx.y;
  const float* in = (by == 0) ? i0 : (by == 1) ? i1 : (by == 2) ? i2 : i3;
  unsigned short* o = out + (size_t)by * n;
  int i = (blockIdx.x * 256 + threadIdx.x) * 8;
  if (i >= n) return;
  const float4* p = (const float4*)(in + i);
  float4 a = p[0], b = p[1];
  union { unsigned short u[8]; uint4 v; } r;
  r.u[0] = f2bf(a.x); r.u[1] = f2bf(a.y); r.u[2] = f2bf(a.z); r.u[3] = f2bf(a.w);
  r.u[4] = f2bf(b.x); r.u[5] = f2bf(b.y); r.u[6] = f2bf(b.z); r.u[7] = f2bf(b.w);
  *(uint4*)(o + i) = r.v;
}

// ---------------- GEMM: C[M,N] = f(A[M,K] * B[N,K]^T + bias) ----------------
// m97-style: single 32KB LDS buffer, stage -> vmcnt(0)+barrier -> 32 MFMA -> barrier.
// A/B staged with per-8-row XOR chunk swizzle -> conflict-free fragment reads.
template <typename CT>
__global__ __launch_bounds__(256)
void gemm_bt(const unsigned short* __restrict__ A, const unsigned short* __restrict__ B,
             const float* __restrict__ b0, const float* __restrict__ b1,
             const float* __restrict__ b2, CT* __restrict__ C, int M, int N, int K,
             int qcols, float alphaQ) {
  __shared__ unsigned short As[128 * 64];
  __shared__ unsigned short Bs[128 * 64];
  const int t = threadIdx.x;
  const int l = t & 63;
  const int w = t >> 6;
  const int wr = w >> 1, wc = w & 1;
  const int l15 = l & 15, lg = l >> 4;
  const int m0 = blockIdx.y * 128, n0 = blockIdx.x * 128;

  f32x4 acc[4][4] = {};

  const int srow = t >> 3;           // 0..31
  const int sc8 = t & 7;             // dest 16B chunk
  const int kssw = sc8 ^ (srow & 7); // XOR-swizzled source chunk

  const unsigned short* ap = A + (size_t)(m0 + srow) * K + kssw * 8;
  const unsigned short* bp = B + (size_t)(n0 + srow) * K + kssw * 8;

  const int nt = K >> 6;
  for (int kt = 0; kt < nt; ++kt) {
    const int k0 = kt * 64;
    #pragma unroll
    for (int j = 0; j < 4; ++j) {
      GLOAD_LDS16(ap + (size_t)(j * 32) * K + k0, &As[(j * 32 + srow) * 64 + sc8 * 8]);
      GLOAD_LDS16(bp + (size_t)(j * 32) * K + k0, &Bs[(j * 32 + srow) * 64 + sc8 * 8]);
    }
    asm volatile("s_waitcnt vmcnt(0)" ::: "memory");
    __builtin_amdgcn_s_barrier();
    __builtin_amdgcn_sched_barrier(0);

    __builtin_amdgcn_s_setprio(1);
    #pragma unroll
    for (int kk = 0; kk < 2; ++kk) {
      short8 af[4], bfr[4];
      #pragma unroll
      for (int m = 0; m < 4; ++m) {
        int row = wr * 64 + m * 16 + l15;
        af[m] = *(const short8*)&As[row * 64 + (((kk * 4 + lg) ^ (row & 7)) * 8)];
      }
      #pragma unroll
      for (int n = 0; n < 4; ++n) {
        int row = wc * 64 + n * 16 + l15;
        bfr[n] = *(const short8*)&Bs[row * 64 + (((kk * 4 + lg) ^ (row & 7)) * 8)];
      }
      #pragma unroll
      for (int m = 0; m < 4; ++m)
        #pragma unroll
        for (int n = 0; n < 4; ++n)
          acc[m][n] = __builtin_amdgcn_mfma_f32_16x16x32_bf16(af[m], bfr[n], acc[m][n], 0, 0, 0);
    }
    __builtin_amdgcn_s_setprio(0);

    __builtin_amdgcn_s_barrier();
    __builtin_amdgcn_sched_barrier(0);
  }

  #pragma unroll
  for (int m = 0; m < 4; ++m) {
    #pragma unroll
    for (int n = 0; n < 4; ++n) {
      int col = n0 + wc * 64 + n * 16 + l15;
      const float* bp2 = (col < 1024) ? b0 : (col < 2048) ? b1 : b2;
      float bz = bp2[col & 1023];
      #pragma unroll
      for (int r = 0; r < 4; ++r) {
        int row = m0 + wr * 64 + m * 16 + lg * 4 + r;
        float v = acc[m][n][r] + bz;
        if (col < qcols) v *= alphaQ;
        if constexpr (sizeof(CT) == 2) {
          C[(size_t)row * N + col] = (CT)f2bf(v);
        } else {
          C[(size_t)row * N + col] = v;
        }
      }
    }
  }
}

// ---------------- causal flash attention: 32x32 MFMA, swapped QK^T, register-P ----------------
// Fixed-shift exp2 softmax => partial results are ADDITIVE across kv-splits:
// o = o0+o1, lacc = l0+l1 exactly. Heavy q-blocks (qb>=8) are split into two
// independent kv-half blocks writing unnormalized f32 partials; combine_kernel
// adds + normalizes. Light blocks (qb<=7) write AO directly.
// mode=1: grid 1536 (j=id>>6: j<16 -> heavy half [qb=15-(j>>1), half=j&1];
//         j>=16 -> light qb=23-j). mode=0: grid 1024, all unsplit (ws fallback).
__global__ __launch_bounds__(256, 2)
void attn_kernel(const unsigned short* __restrict__ QKV, unsigned short* __restrict__ AO,
                 float* __restrict__ po, float* __restrict__ pl, int mode) {
  __shared__ unsigned short Ks[2][64 * 64];
  __shared__ unsigned int Vt32[64 * 33];       // [d][pair-slot] packed 2xbf16; stride 33 dwords

  const int t = threadIdx.x;
  const int l = t & 63;
  const int wave = t >> 6;
  const int l31 = l & 31, lh = l >> 5;
  const int id = blockIdx.x;
  const int bh = id & 63;         // same-head blocks differ by 64 -> same XCD
  const int b = bh >> 4, h = bh & 15;

  int qb, kvA, kvB, half = -1, slot = 0;
  if (mode) {
    const int j = id >> 6;
    if (j < 16) {                 // heavy q-block, one kv half
      qb = 15 - (j >> 1);
      half = j & 1;
      slot = (j >> 1) * 64 + bh;
      const int mid = qb + 1;
      kvA = half ? mid : 0;
      kvB = half ? 2 * qb + 2 : mid;
    } else {                      // light q-block, full range
      qb = 23 - j;
      kvA = 0; kvB = 2 * qb + 2;
    }
  } else {
    qb = 15 - (id >> 6);
    kvA = 0; kvB = 2 * qb + 2;
  }

  const size_t hbase = (size_t)b * SEQ * QKVSTR + h * DK;
  const size_t hbaseO = (size_t)b * SEQ * D_MODEL + h * DK;
  const int qloc = wave * 32 + l31;
  const int q = qb * 128 + qloc;               // this lane's q row

  // hoisted Q fragments (B-operand): qf[kg][j] = Q[q][kg*16 + lh*8 + j]
  short8 qf[4];
  {
    const unsigned short* qp = QKV + hbase + (size_t)q * QKVSTR + lh * 8;
    qf[0] = *(const short8*)(qp);
    qf[1] = *(const short8*)(qp + 16);
    qf[2] = *(const short8*)(qp + 32);
    qf[3] = *(const short8*)(qp + 48);
  }

  f32x16 o0 = {}, o1 = {};        // O^T accumulators: d-tiles 0 (d 0..31), 1 (d 32..63)
  float lacc = 0.f;               // lane-local partial row-sum (combined once at end)

  // K staging map: thread t covers row srow(+32), 16B chunk sc8; source chunk XOR-swizzled
  const int srow = t >> 3, sc8 = t & 7;
  const int kssw = sc8 ^ (srow & 7);
  // V staging: thread covers kv-pair vp_, 8 d values; slot = swap bits 1,2 of vp_
  const int vp_ = t & 31;
  const int vdh = (t >> 5) * 8;
  const int vpos = (vp_ & 0x19) | ((vp_ & 2) << 1) | ((vp_ & 4) >> 1);

  auto issueK = [&](int kvt, int buf) {
    const unsigned short* kp = QKV + hbase + 1024 + (size_t)(kvt * 64 + srow) * QKVSTR + kssw * 8;
    GLOAD_LDS16(kp, &Ks[buf][srow * 64 + sc8 * 8]);
    GLOAD_LDS16(kp + (size_t)32 * QKVSTR, &Ks[buf][(32 + srow) * 64 + sc8 * 8]);
  };

  // prologue: tile kvA staged
  short8 cv0, cv1;
  issueK(kvA, 0);
  {
    const unsigned short* vp = QKV + hbase + 2048 + (size_t)(kvA * 64 + 2 * vp_) * QKVSTR + vdh;
    cv0 = *(const short8*)vp;
    cv1 = *(const short8*)(vp + QKVSTR);
  }

  int p = 0;
  for (int kvt = kvA; kvt < kvB; ++kvt) {
    const int kv0 = kvt * 64;
    // barrier1: my K(t) DMA + V(t) regs arrived; all waves done with Vt(t-1) reads
    asm volatile("s_waitcnt vmcnt(0)" ::: "memory");
    __builtin_amdgcn_s_barrier();
    __builtin_amdgcn_sched_barrier(0);

    // stage V(t) to LDS (packed transpose, permuted slot), then prefetch tile t+1
    #pragma unroll
    for (int j = 0; j < 8; ++j) {
      unsigned int dw = (unsigned int)(unsigned short)cv0[j] |
                        ((unsigned int)(unsigned short)cv1[j] << 16);
      Vt32[(vdh + j) * 33 + vpos] = dw;
    }
    short8 nv0 = cv0, nv1 = cv1;
    if (kvt + 1 < kvB) {
      issueK(kvt + 1, p ^ 1);
      const unsigned short* vp = QKV + hbase + 2048 + (size_t)(kv0 + 64 + 2 * vp_) * QKVSTR + vdh;
      nv0 = *(const short8*)vp;
      nv1 = *(const short8*)(vp + QKVSTR);
    }
    // barrier2: V writes visible; prefetch loads stay in flight (no vmcnt drain)
    asm volatile("s_waitcnt lgkmcnt(0)" ::: "memory");
    __builtin_amdgcn_s_barrier();
    __builtin_amdgcn_sched_barrier(0);

    // ---- swapped QK^T (32x32x16): s0 = S^T[kv 0..31][q], s1 = S^T[kv 32..63][q] ----
    f32x16 s0 = {}, s1 = {};
    __builtin_amdgcn_s_setprio(1);
    #pragma unroll
    for (int kg = 0; kg < 4; ++kg) {
      int row0 = l31;
      int row1 = 32 + l31;
      int c = 2 * kg + lh;
      short8 kf0 = *(const short8*)&Ks[p][row0 * 64 + ((c ^ (row0 & 7)) * 8)];
      short8 kf1 = *(const short8*)&Ks[p][row1 * 64 + ((c ^ (row1 & 7)) * 8)];
      s0 = __builtin_amdgcn_mfma_f32_32x32x16_bf16(kf0, qf[kg], s0, 0, 0, 0);
      s1 = __builtin_amdgcn_mfma_f32_32x32x16_bf16(kf1, qf[kg], s1, 0, 0, 0);
    }
    __builtin_amdgcn_s_setprio(0);

    // ---- causal mask (only the global last two kv-tiles reach here) ----
    if (kvt >= 2 * qb) {
      #pragma unroll
      for (int g = 0; g < 4; ++g)
        #pragma unroll
        for (int e = 0; e < 4; ++e) {
          int kvl = 8 * g + e + 4 * lh;
          if (kv0 + kvl > q)      s0[4 * g + e] = -INFINITY;
          if (kv0 + 32 + kvl > q) s1[4 * g + e] = -INFINITY;
        }
    }

    // ---- softmax, fixed shift: P = exp2(s); lane-local partial sums only ----
    {
      float ps0 = 0.f, ps1 = 0.f, ps2 = 0.f, ps3 = 0.f;
      #pragma unroll
      for (int i = 0; i < 4; ++i) {
        s0[i]      = EXP2(s0[i]);      ps0 += s0[i];
        s0[i + 4]  = EXP2(s0[i + 4]);  ps1 += s0[i + 4];
        s0[i + 8]  = EXP2(s0[i + 8]);  ps2 += s0[i + 8];
        s0[i + 12] = EXP2(s0[i + 12]); ps3 += s0[i + 12];
      }
      #pragma unroll
      for (int i = 0; i < 4; ++i) {
        s1[i]      = EXP2(s1[i]);      ps0 += s1[i];
        s1[i + 4]  = EXP2(s1[i + 4]);  ps1 += s1[i + 4];
        s1[i + 8]  = EXP2(s1[i + 8]);  ps2 += s1[i + 8];
        s1[i + 12] = EXP2(s1[i + 12]); ps3 += s1[i + 12];
      }
      lacc += (ps0 + ps1) + (ps2 + ps3);
    }

    // ---- PV: O^T += V^T * P^T, P packed in-register per 16-kv window ----
    __builtin_amdgcn_s_setprio(1);
    #pragma unroll
    for (int win = 0; win < 4; ++win) {
      const int base = 8 * (win & 1);
      uint4 pu;
      if (win < 2) {
        pu.x = cvt_pk_bf16(s0[base + 0], s0[base + 1]);
        pu.y = cvt_pk_bf16(s0[base + 2], s0[base + 3]);
        pu.z = cvt_pk_bf16(s0[base + 4], s0[base + 5]);
        pu.w = cvt_pk_bf16(s0[base + 6], s0[base + 7]);
      } else {
        pu.x = cvt_pk_bf16(s1[base + 0], s1[base + 1]);
        pu.y = cvt_pk_bf16(s1[base + 2], s1[base + 3]);
        pu.z = cvt_pk_bf16(s1[base + 4], s1[base + 5]);
        pu.w = cvt_pk_bf16(s1[base + 6], s1[base + 7]);
      }
      short8 pb = __builtin_bit_cast(short8, pu);
      uint4 u0 = *(const uint4*)&Vt32[(l31) * 33 + win * 8 + lh * 4];
      uint4 u1 = *(const uint4*)&Vt32[(32 + l31) * 33 + win * 8 + lh * 4];
      o0 = __builtin_amdgcn_mfma_f32_32x32x16_bf16(__builtin_bit_cast(short8, u0), pb, o0, 0, 0, 0);
      o1 = __builtin_amdgcn_mfma_f32_32x32x16_bf16(__builtin_bit_cast(short8, u1), pb, o1, 0, 0, 0);
    }
    __builtin_amdgcn_s_setprio(0);

    cv0 = nv0; cv1 = nv1;
    p ^= 1;
  }

  // ---- combine lane-half partial sums once ----
  lacc += __shfl_xor(lacc, 32, 64);

  if (half >= 0) {
    // heavy kv-half: store UNNORMALIZED f32 partials + lacc (additive across halves)
    float* myo = po + ((size_t)(slot * 2 + half) * 128 + qloc) * 64;
    #pragma unroll
    for (int g = 0; g < 4; ++g) {
      int d0 = 8 * g + 4 * lh;
      float4 f0 = make_float4(o0[4 * g + 0], o0[4 * g + 1], o0[4 * g + 2], o0[4 * g + 3]);
      float4 f1 = make_float4(o1[4 * g + 0], o1[4 * g + 1], o1[4 * g + 2], o1[4 * g + 3]);
      *(float4*)(myo + d0) = f0;
      *(float4*)(myo + 32 + d0) = f1;
    }
    if (lh == 0) pl[(size_t)(slot * 2 + half) * 128 + qloc] = lacc;
  } else {
    // full-range block: normalize and write AO
    float inv = 1.f / lacc;
    unsigned short* op = AO + hbaseO + (size_t)q * D_MODEL;
    #pragma unroll
    for (int g = 0; g < 4; ++g) {
      int d0 = 8 * g + 4 * lh;
      ushort4 v0, v1;
      v0.x = f2bf(o0[4 * g + 0] * inv); v0.y = f2bf(o0[4 * g + 1] * inv);
      v0.z = f2bf(o0[4 * g + 2] * inv); v0.w = f2bf(o0[4 * g + 3] * inv);
      v1.x = f2bf(o1[4 * g + 0] * inv); v1.y = f2bf(o1[4 * g + 1] * inv);
      v1.z = f2bf(o1[4 * g + 2] * inv); v1.w = f2bf(o1[4 * g + 3] * inv);
      *(ushort4*)(op + d0) = v0;
      *(ushort4*)(op + 32 + d0) = v1;
    }
  }
}

// ---------------- combine: AO[heavy rows] = (o_half0 + o_half1) / (l0 + l1) ----------------
// rows = slot*128 + qloc, slot = s7*64 + bh with qb = 15 - s7. 16 threads per row (4 d each).
__global__ __launch_bounds__(256)
void combine_kernel(const float* __restrict__ po, const float* __restrict__ pl,
                    unsigned short* __restrict__ AO) {
  const int idx = blockIdx.x * 256 + threadIdx.x;
  const int row = idx >> 4;            // 0..65535
  const int dch = (idx & 15) * 4;
  const int slot = row >> 7, qloc = row & 127;
  const float4 a = *(const float4*)(po + ((size_t)(slot * 2) * 128 + qloc) * 64 + dch);
  const float4 c = *(const float4*)(po + ((size_t)(slot * 2 + 1) * 128 + qloc) * 64 + dch);
  const float lsum = pl[(size_t)(slot * 2) * 128 + qloc] + pl[(size_t)(slot * 2 + 1) * 128 + qloc];
  const float inv = 1.f / lsum;
  const int s7 = slot >> 6, bh = slot & 63;
  const int qb = 15 - s7;
  const int q = qb * 128 + qloc;
  const int b = bh >> 4, h = bh & 15;
  unsigned short* op = AO + (size_t)b * SEQ * D_MODEL + (size_t)q * D_MODEL + h * DK + dch;
  ushort4 v;
  v.x = f2bf((a.x + c.x) * inv);
  v.y = f2bf((a.y + c.y) * inv);
  v.z = f2bf((a.z + c.z) * inv);
  v.w = f2bf((a.w + c.w) * inv);
  *(ushort4*)op = v;
}

extern "C" void kernel_launch(void* const* d_in, const int* in_sizes, int n_in,
                              void* d_out, int out_size, void* d_ws, size_t ws_size,
                              hipStream_t stream) {
  const float* x   = (const float*)d_in[0];
  const float* WQw = (const float*)d_in[1];
  const float* WQb = (const float*)d_in[2];
  const float* WKw = (const float*)d_in[3];
  const float* WKb = (const float*)d_in[4];
  const float* WVw = (const float*)d_in[5];
  const float* WVb = (const float*)d_in[6];
  const float* WOw = (const float*)d_in[7];
  const float* WOb = (const float*)d_in[8];
  float* out = (float*)d_out;

  const int M = BATCH * SEQ;       // 8192
  const int D = D_MODEL;           // 1024
  const int NX = M * D;            // 8388608
  const int NW = D * D;            // 1048576

  unsigned short* xb = (unsigned short*)d_ws;
  unsigned short* wq = xb + NX;        // wq|wk|wv|wo contiguous (cvt4)
  unsigned short* wo = wq + 3 * NW;
  unsigned short* QKVb = wq + 4 * NW;  // [8192][3072]
  unsigned short* AOb = xb;            // reuse x-bf16 region after QKV projection

  // split-kv partials (heavy q-blocks qb>=8): po 512 slots x 2 halves x 128q x 64d f32
  float* po = (float*)(QKVb + (size_t)M * 3072);
  float* pl = po + (size_t)512 * 2 * 128 * 64;
  const size_t need = (size_t)((char*)(pl + 512 * 2 * 128) - (char*)d_ws);
  const int split = (ws_size >= need) ? 1 : 0;

  cvt_kernel<<<NX / 8 / 256, 256, 0, stream>>>(x, xb, NX);
  cvt4_kernel<<<dim3(NW / 8 / 256, 4), 256, 0, stream>>>(WQw, WKw, WVw, WOw, wq, NW);

  const float qscale = 0.125f * 1.4426950408889634f;  // softmax scale + log2(e) folded into Q
  // fused QKV projection: [8192,1024] x [3072,1024]^T -> [8192,3072]
  gemm_bt<unsigned short><<<dim3(3 * D / 128, M / 128), 256, 0, stream>>>(
      xb, wq, WQb, WKb, WVb, QKVb, M, 3 * D, D, 1024, qscale);

  if (split) {
    attn_kernel<<<1536, 256, 0, stream>>>(QKVb, AOb, po, pl, 1);
    combine_kernel<<<4096, 256, 0, stream>>>(po, pl, AOb);
  } else {
    attn_kernel<<<1024, 256, 0, stream>>>(QKVb, AOb, po, pl, 0);
  }

  gemm_bt<float><<<dim3(D / 128, M / 128), 256, 0, stream>>>(
      AOb, wo, WOb, WOb, WOb, out, M, D, D, 0, 1.0f);
}

// Round 21
// 149.161 us; speedup vs baseline: 1.0840x; 1.0840x over previous
//
#include <hip/hip_runtime.h>
#include <hip/hip_bf16.h>
#include <stdint.h>

#define D_MODEL 1024
#define NHEAD 16
#define SEQ 2048
#define BATCH 4
#define DK 64
#define QKVSTR 3072

typedef __attribute__((ext_vector_type(8))) short short8;
typedef __attribute__((ext_vector_type(4))) float f32x4;
typedef __attribute__((ext_vector_type(16))) float f32x16;

#if __has_builtin(__builtin_amdgcn_exp2f)
#define EXP2(x) __builtin_amdgcn_exp2f(x)
#else
#define EXP2(x) exp2f(x)
#endif

__device__ inline unsigned short f2bf(float f) {
  unsigned int u = __builtin_bit_cast(unsigned int, f);
  unsigned int r = (u + 0x7fffu + ((u >> 16) & 1u)) >> 16;
  return (unsigned short)r;
}

__device__ inline unsigned int cvt_pk_bf16(float lo, float hi) {
  unsigned int d;
  asm("v_cvt_pk_bf16_f32 %0, %1, %2" : "=v"(d) : "v"(lo), "v"(hi));
  return d;
}

#define GLOAD_LDS16(g, l) \
  __builtin_amdgcn_global_load_lds((const __attribute__((address_space(1))) unsigned int*)(g), \
      (__attribute__((address_space(3))) unsigned int*)(l), 16, 0, 0)

// ---------------- f32 -> bf16 convert: x (blocks 0..nx-1) + 4 weights (512 blocks each) ----------------
__global__ void cvt5_kernel(const float* __restrict__ x, const float* __restrict__ w0,
                            const float* __restrict__ w1, const float* __restrict__ w2,
                            const float* __restrict__ w3, unsigned short* __restrict__ xo,
                            unsigned short* __restrict__ wo_, int nx, int nw) {
  const int id = blockIdx.x;
  const int xblocks = nx / 2048;
  const float* in;
  unsigned short* o;
  int i;
  if (id < xblocks) {
    in = x; o = xo;
    i = (id * 256 + threadIdx.x) * 8;
    if (i >= nx) return;
  } else {
    const int wb = (id - xblocks) >> 9;            // weight index 0..3
    const int wi = (id - xblocks) & 511;
    in = (wb == 0) ? w0 : (wb == 1) ? w1 : (wb == 2) ? w2 : w3;
    o = wo_ + (size_t)wb * nw;
    i = (wi * 256 + threadIdx.x) * 8;
    if (i >= nw) return;
  }
  const float4* p = (const float4*)(in + i);
  float4 a = p[0], b = p[1];
  union { unsigned short u[8]; uint4 v; } r;
  r.u[0] = f2bf(a.x); r.u[1] = f2bf(a.y); r.u[2] = f2bf(a.z); r.u[3] = f2bf(a.w);
  r.u[4] = f2bf(b.x); r.u[5] = f2bf(b.y); r.u[6] = f2bf(b.z); r.u[7] = f2bf(b.w);
  *(uint4*)(o + i) = r.v;
}

// ---------------- GEMM: C[M,N] = f(A[M,K] * B[N,K]^T + bias) ----------------
// m97-style: single 32KB LDS buffer, stage -> vmcnt(0)+barrier -> 32 MFMA -> barrier.
// A/B staged with per-8-row XOR chunk swizzle -> conflict-free fragment reads.
template <typename CT>
__global__ __launch_bounds__(256)
void gemm_bt(const unsigned short* __restrict__ A, const unsigned short* __restrict__ B,
             const float* __restrict__ b0, const float* __restrict__ b1,
             const float* __restrict__ b2, CT* __restrict__ C, int M, int N, int K,
             int qcols, float alphaQ) {
  __shared__ unsigned short As[128 * 64];
  __shared__ unsigned short Bs[128 * 64];
  const int t = threadIdx.x;
  const int l = t & 63;
  const int w = t >> 6;
  const int wr = w >> 1, wc = w & 1;
  const int l15 = l & 15, lg = l >> 4;
  const int m0 = blockIdx.y * 128, n0 = blockIdx.x * 128;

  f32x4 acc[4][4] = {};

  const int srow = t >> 3;           // 0..31
  const int sc8 = t & 7;             // dest 16B chunk
  const int kssw = sc8 ^ (srow & 7); // XOR-swizzled source chunk

  const unsigned short* ap = A + (size_t)(m0 + srow) * K + kssw * 8;
  const unsigned short* bp = B + (size_t)(n0 + srow) * K + kssw * 8;

  const int nt = K >> 6;
  for (int kt = 0; kt < nt; ++kt) {
    const int k0 = kt * 64;
    #pragma unroll
    for (int j = 0; j < 4; ++j) {
      GLOAD_LDS16(ap + (size_t)(j * 32) * K + k0, &As[(j * 32 + srow) * 64 + sc8 * 8]);
      GLOAD_LDS16(bp + (size_t)(j * 32) * K + k0, &Bs[(j * 32 + srow) * 64 + sc8 * 8]);
    }
    asm volatile("s_waitcnt vmcnt(0)" ::: "memory");
    __builtin_amdgcn_s_barrier();
    __builtin_amdgcn_sched_barrier(0);

    __builtin_amdgcn_s_setprio(1);
    #pragma unroll
    for (int kk = 0; kk < 2; ++kk) {
      short8 af[4], bfr[4];
      #pragma unroll
      for (int m = 0; m < 4; ++m) {
        int row = wr * 64 + m * 16 + l15;
        af[m] = *(const short8*)&As[row * 64 + (((kk * 4 + lg) ^ (row & 7)) * 8)];
      }
      #pragma unroll
      for (int n = 0; n < 4; ++n) {
        int row = wc * 64 + n * 16 + l15;
        bfr[n] = *(const short8*)&Bs[row * 64 + (((kk * 4 + lg) ^ (row & 7)) * 8)];
      }
      #pragma unroll
      for (int m = 0; m < 4; ++m)
        #pragma unroll
        for (int n = 0; n < 4; ++n)
          acc[m][n] = __builtin_amdgcn_mfma_f32_16x16x32_bf16(af[m], bfr[n], acc[m][n], 0, 0, 0);
    }
    __builtin_amdgcn_s_setprio(0);

    __builtin_amdgcn_s_barrier();
    __builtin_amdgcn_sched_barrier(0);
  }

  #pragma unroll
  for (int m = 0; m < 4; ++m) {
    #pragma unroll
    for (int n = 0; n < 4; ++n) {
      int col = n0 + wc * 64 + n * 16 + l15;
      const float* bp2 = (col < 1024) ? b0 : (col < 2048) ? b1 : b2;
      float bz = bp2[col & 1023];
      #pragma unroll
      for (int r = 0; r < 4; ++r) {
        int row = m0 + wr * 64 + m * 16 + lg * 4 + r;
        float v = acc[m][n][r] + bz;
        if (col < qcols) v *= alphaQ;
        if constexpr (sizeof(CT) == 2) {
          C[(size_t)row * N + col] = (CT)f2bf(v);
        } else {
          C[(size_t)row * N + col] = v;
        }
      }
    }
  }
}

// ---------------- causal flash attention: 32x32 MFMA, swapped QK^T, register-P ----------------
// QKV: [B*S, 3072] bf16 rows = [Q | K | V], head h at col h*64 within each section.
// Q pre-scaled by 0.125*log2(e); fixed-shift exp2 softmax (scores are O(1) -> no overflow;
// normalization o/lacc makes the missing per-row shift exact).
// Wave covers 32 q-rows; lane owns ONE q = q0 + (lane&31) (lane-local stats).
// lacc is accumulated as lane-local PARTIAL sums; single cross-lane combine at the end.
// PV as O^T = V^T * P^T: P packed in-register (cvt_pk); kv permutation (swap bits 2,3
// of kv mod 16) applied to BOTH P slot-order (implicit) and V staging slot (vpos).
// Pipeline: K(t+1) DMA (dbuf Ks) + V(t+1) reg loads in flight across barrier2 (lgkm-only).
__global__ __launch_bounds__(256, 2)
void attn_kernel(const unsigned short* __restrict__ QKV, unsigned short* __restrict__ AO) {
  __shared__ unsigned short Ks[2][64 * 64];
  __shared__ unsigned int Vt32[64 * 33];       // [d][pair-slot] packed 2xbf16; stride 33 dwords

  const int t = threadIdx.x;
  const int l = t & 63;
  const int wave = t >> 6;
  const int l31 = l & 31, lh = l >> 5;
  const int id = blockIdx.x;
  const int qb = 15 - (id >> 6);  // heaviest q-blocks dispatched first
  const int bh = id & 63;         // same-head blocks differ by 64 -> same XCD
  const int b = bh >> 4, h = bh & 15;
  const size_t hbase = (size_t)b * SEQ * QKVSTR + h * DK;
  const size_t hbaseO = (size_t)b * SEQ * D_MODEL + h * DK;

  const int q = qb * 128 + wave * 32 + l31;    // this lane's q row

  // hoisted Q fragments (B-operand): qf[kg][j] = Q[q][kg*16 + lh*8 + j]
  short8 qf[4];
  {
    const unsigned short* qp = QKV + hbase + (size_t)q * QKVSTR + lh * 8;
    qf[0] = *(const short8*)(qp);
    qf[1] = *(const short8*)(qp + 16);
    qf[2] = *(const short8*)(qp + 32);
    qf[3] = *(const short8*)(qp + 48);
  }

  f32x16 o0 = {}, o1 = {};        // O^T accumulators: d-tiles 0 (d 0..31), 1 (d 32..63)
  float lacc = 0.f;               // lane-local partial row-sum (combined once at end)

  // K staging map: thread t covers row srow(+32), 16B chunk sc8; source chunk XOR-swizzled
  const int srow = t >> 3, sc8 = t & 7;
  const int kssw = sc8 ^ (srow & 7);
  // V staging: thread covers kv-pair vp_, 8 d values; slot = swap bits 1,2 of vp_ (pi on kv bits 2,3)
  const int vp_ = t & 31;
  const int vdh = (t >> 5) * 8;
  const int vpos = (vp_ & 0x19) | ((vp_ & 2) << 1) | ((vp_ & 4) >> 1);

  auto issueK = [&](int kvt, int buf) {
    const unsigned short* kp = QKV + hbase + 1024 + (size_t)(kvt * 64 + srow) * QKVSTR + kssw * 8;
    GLOAD_LDS16(kp, &Ks[buf][srow * 64 + sc8 * 8]);
    GLOAD_LDS16(kp + (size_t)32 * QKVSTR, &Ks[buf][(32 + srow) * 64 + sc8 * 8]);
  };

  const int ntiles = 2 * qb + 2;

  // prologue: tile 0 staged
  short8 cv0, cv1;
  issueK(0, 0);
  {
    const unsigned short* vp = QKV + hbase + 2048 + (size_t)(2 * vp_) * QKVSTR + vdh;
    cv0 = *(const short8*)vp;
    cv1 = *(const short8*)(vp + QKVSTR);
  }

  int p = 0;
  for (int kvt = 0; kvt < ntiles; ++kvt) {
    const int kv0 = kvt * 64;
    // barrier1: my K(t) DMA + V(t) regs arrived; all waves done with Vt(t-1) reads
    asm volatile("s_waitcnt vmcnt(0)" ::: "memory");
    __builtin_amdgcn_s_barrier();
    __builtin_amdgcn_sched_barrier(0);

    // stage V(t) to LDS (packed transpose, permuted slot), then prefetch tile t+1
    #pragma unroll
    for (int j = 0; j < 8; ++j) {
      unsigned int dw = (unsigned int)(unsigned short)cv0[j] |
                        ((unsigned int)(unsigned short)cv1[j] << 16);
      Vt32[(vdh + j) * 33 + vpos] = dw;
    }
    short8 nv0 = cv0, nv1 = cv1;
    if (kvt + 1 < ntiles) {
      issueK(kvt + 1, p ^ 1);
      const unsigned short* vp = QKV + hbase + 2048 + (size_t)(kv0 + 64 + 2 * vp_) * QKVSTR + vdh;
      nv0 = *(const short8*)vp;
      nv1 = *(const short8*)(vp + QKVSTR);
    }
    // barrier2: V writes visible; prefetch loads stay in flight (no vmcnt drain)
    asm volatile("s_waitcnt lgkmcnt(0)" ::: "memory");
    __builtin_amdgcn_s_barrier();
    __builtin_amdgcn_sched_barrier(0);

    // ---- swapped QK^T (32x32x16): s0 = S^T[kv 0..31][q], s1 = S^T[kv 32..63][q] ----
    f32x16 s0 = {}, s1 = {};
    __builtin_amdgcn_s_setprio(1);
    #pragma unroll
    for (int kg = 0; kg < 4; ++kg) {
      int row0 = l31;            // kv-local, half 0
      int row1 = 32 + l31;       // kv-local, half 1
      int c = 2 * kg + lh;
      short8 kf0 = *(const short8*)&Ks[p][row0 * 64 + ((c ^ (row0 & 7)) * 8)];
      short8 kf1 = *(const short8*)&Ks[p][row1 * 64 + ((c ^ (row1 & 7)) * 8)];
      s0 = __builtin_amdgcn_mfma_f32_32x32x16_bf16(kf0, qf[kg], s0, 0, 0, 0);
      s1 = __builtin_amdgcn_mfma_f32_32x32x16_bf16(kf1, qf[kg], s1, 0, 0, 0);
    }
    __builtin_amdgcn_s_setprio(0);

    // ---- causal mask (last two kv-tiles only) ----
    if (kvt >= ntiles - 2) {
      #pragma unroll
      for (int g = 0; g < 4; ++g)
        #pragma unroll
        for (int e = 0; e < 4; ++e) {
          int kvl = 8 * g + e + 4 * lh;
          if (kv0 + kvl > q)      s0[4 * g + e] = -INFINITY;
          if (kv0 + 32 + kvl > q) s1[4 * g + e] = -INFINITY;
        }
    }

    // ---- softmax, fixed shift: P = exp2(s); lane-local partial sums only ----
    {
      float ps0 = 0.f, ps1 = 0.f, ps2 = 0.f, ps3 = 0.f;
      #pragma unroll
      for (int i = 0; i < 4; ++i) {
        s0[i]      = EXP2(s0[i]);      ps0 += s0[i];
        s0[i + 4]  = EXP2(s0[i + 4]);  ps1 += s0[i + 4];
        s0[i + 8]  = EXP2(s0[i + 8]);  ps2 += s0[i + 8];
        s0[i + 12] = EXP2(s0[i + 12]); ps3 += s0[i + 12];
      }
      #pragma unroll
      for (int i = 0; i < 4; ++i) {
        s1[i]      = EXP2(s1[i]);      ps0 += s1[i];
        s1[i + 4]  = EXP2(s1[i + 4]);  ps1 += s1[i + 4];
        s1[i + 8]  = EXP2(s1[i + 8]);  ps2 += s1[i + 8];
        s1[i + 12] = EXP2(s1[i + 12]); ps3 += s1[i + 12];
      }
      lacc += (ps0 + ps1) + (ps2 + ps3);
    }

    // ---- PV: O^T += V^T * P^T, P packed in-register per 16-kv window ----
    __builtin_amdgcn_s_setprio(1);
    #pragma unroll
    for (int win = 0; win < 4; ++win) {
      const int base = 8 * (win & 1);
      uint4 pu;
      if (win < 2) {
        pu.x = cvt_pk_bf16(s0[base + 0], s0[base + 1]);
        pu.y = cvt_pk_bf16(s0[base + 2], s0[base + 3]);
        pu.z = cvt_pk_bf16(s0[base + 4], s0[base + 5]);
        pu.w = cvt_pk_bf16(s0[base + 6], s0[base + 7]);
      } else {
        pu.x = cvt_pk_bf16(s1[base + 0], s1[base + 1]);
        pu.y = cvt_pk_bf16(s1[base + 2], s1[base + 3]);
        pu.z = cvt_pk_bf16(s1[base + 4], s1[base + 5]);
        pu.w = cvt_pk_bf16(s1[base + 6], s1[base + 7]);
      }
      short8 pb = __builtin_bit_cast(short8, pu);
      uint4 u0 = *(const uint4*)&Vt32[(l31) * 33 + win * 8 + lh * 4];
      uint4 u1 = *(const uint4*)&Vt32[(32 + l31) * 33 + win * 8 + lh * 4];
      o0 = __builtin_amdgcn_mfma_f32_32x32x16_bf16(__builtin_bit_cast(short8, u0), pb, o0, 0, 0, 0);
      o1 = __builtin_amdgcn_mfma_f32_32x32x16_bf16(__builtin_bit_cast(short8, u1), pb, o1, 0, 0, 0);
    }
    __builtin_amdgcn_s_setprio(0);

    cv0 = nv0; cv1 = nv1;
    p ^= 1;
  }

  // ---- combine lane-half partial sums once; write normalized output ----
  lacc += __shfl_xor(lacc, 32, 64);
  float inv = 1.f / lacc;
  unsigned short* op = AO + hbaseO + (size_t)q * D_MODEL;
  #pragma unroll
  for (int g = 0; g < 4; ++g) {
    int d0 = 8 * g + 4 * lh;
    ushort4 v0, v1;
    v0.x = f2bf(o0[4 * g + 0] * inv); v0.y = f2bf(o0[4 * g + 1] * inv);
    v0.z = f2bf(o0[4 * g + 2] * inv); v0.w = f2bf(o0[4 * g + 3] * inv);
    v1.x = f2bf(o1[4 * g + 0] * inv); v1.y = f2bf(o1[4 * g + 1] * inv);
    v1.z = f2bf(o1[4 * g + 2] * inv); v1.w = f2bf(o1[4 * g + 3] * inv);
    *(ushort4*)(op + d0) = v0;
    *(ushort4*)(op + 32 + d0) = v1;
  }
}

extern "C" void kernel_launch(void* const* d_in, const int* in_sizes, int n_in,
                              void* d_out, int out_size, void* d_ws, size_t ws_size,
                              hipStream_t stream) {
  const float* x   = (const float*)d_in[0];
  const float* WQw = (const float*)d_in[1];
  const float* WQb = (const float*)d_in[2];
  const float* WKw = (const float*)d_in[3];
  const float* WKb = (const float*)d_in[4];
  const float* WVw = (const float*)d_in[5];
  const float* WVb = (const float*)d_in[6];
  const float* WOw = (const float*)d_in[7];
  const float* WOb = (const float*)d_in[8];
  float* out = (float*)d_out;

  const int M = BATCH * SEQ;       // 8192
  const int D = D_MODEL;           // 1024
  const int NX = M * D;            // 8388608
  const int NW = D * D;            // 1048576

  unsigned short* xb = (unsigned short*)d_ws;
  unsigned short* wq = xb + NX;        // wq|wk|wv|wo contiguous
  unsigned short* wo = wq + 3 * NW;
  unsigned short* QKVb = wq + 4 * NW;  // [8192][3072]
  unsigned short* AOb = xb;            // reuse x-bf16 region after QKV projection

  // single convert dispatch: x (4096 blocks) + 4 weights (512 blocks each)
  cvt5_kernel<<<NX / 2048 + 4 * (NW / 2048), 256, 0, stream>>>(
      x, WQw, WKw, WVw, WOw, xb, wq, NX, NW);

  const float qscale = 0.125f * 1.4426950408889634f;  // softmax scale + log2(e) folded into Q
  // fused QKV projection: [8192,1024] x [3072,1024]^T -> [8192,3072]
  gemm_bt<unsigned short><<<dim3(3 * D / 128, M / 128), 256, 0, stream>>>(
      xb, wq, WQb, WKb, WVb, QKVb, M, 3 * D, D, 1024, qscale);

  attn_kernel<<<1024, 256, 0, stream>>>(QKVb, AOb);

  gemm_bt<float><<<dim3(D / 128, M / 128), 256, 0, stream>>>(
      AOb, wo, WOb, WOb, WOb, out, M, D, D, 0, 1.0f);
}